// Round 10
// baseline (330.310 us; speedup 1.0000x reference)
//
#include <hip/hip_runtime.h>
#include <hip/hip_bf16.h>
#include <math.h>

// Problem constants
#define B_  4
#define S_  2048
#define D_  1024
#define H_  16
#define HD_ 64

typedef __bf16 bf16;
typedef __bf16 bf16x4 __attribute__((ext_vector_type(4)));
typedef __bf16 bf16x8 __attribute__((ext_vector_type(8)));
typedef float  floatx4 __attribute__((ext_vector_type(4)));

// log2(e)/8: folds the 1/sqrt(64) attention scale AND the exp->exp2 change
// of base into the Q projection epilogue.
#define QSCALE 0.18033688011112042f

// Async global->LDS DMA, 16B/lane. LDS dest = wave-uniform base + lane*16.
__device__ __forceinline__ void async_load16(const bf16* g, bf16* l) {
  __builtin_amdgcn_global_load_lds(
      (const __attribute__((address_space(1))) void*)g,
      (__attribute__((address_space(3))) void*)l, 16, 0, 0);
}

// ---------------------------------------------------------------------------
// Merged input-cast + weight-transpose (one launch, block-ranged):
// blocks [0,16384): fp32->bf16 cast of X_Q / X_KV (8192 each)
// blocks [16384,20480): fp32 [K][N] -> bf16 [N][K] transpose of 3 weights
// ---------------------------------------------------------------------------
__global__ __launch_bounds__(256) void prep_all(
    const float* __restrict__ xa, bf16* __restrict__ oa,
    const float* __restrict__ xb, bf16* __restrict__ ob,
    const float* __restrict__ qw, bf16* __restrict__ qwT,
    const float* __restrict__ kvw, bf16* __restrict__ kvwT,
    const float* __restrict__ ow, bf16* __restrict__ owT) {
  __shared__ float tile[32][33];
  int bid = blockIdx.x;
  if (bid < 16384) {
    const float* in; bf16* out; int i;
    if (bid < 8192) { in = xa; out = oa; i = (bid * 256 + threadIdx.x) * 4; }
    else            { in = xb; out = ob; i = ((bid - 8192) * 256 + threadIdx.x) * 4; }
    float4 v = *reinterpret_cast<const float4*>(in + i);
    bf16x4 o;
    o[0] = (bf16)v.x; o[1] = (bf16)v.y; o[2] = (bf16)v.z; o[3] = (bf16)v.w;
    *reinterpret_cast<bf16x4*>(out + i) = o;
    return;
  }
  bid -= 16384;
  const float* in; bf16* out; int N, lb;
  if (bid < 1024)      { in = qw;  out = qwT;  N = 1024; lb = bid; }
  else if (bid < 3072) { in = kvw; out = kvwT; N = 2048; lb = bid - 1024; }
  else                 { in = ow;  out = owT;  N = 1024; lb = bid - 3072; }
  int nx = N >> 5;
  int n0 = (lb % nx) * 32, k0 = (lb / nx) * 32;
  int tx = threadIdx.x & 31, ty = threadIdx.x >> 5;  // 32 x 8
  #pragma unroll
  for (int i = ty; i < 32; i += 8)
    tile[i][tx] = in[(size_t)(k0 + i) * N + n0 + tx];
  __syncthreads();
  #pragma unroll
  for (int i = ty; i < 32; i += 8)
    out[(size_t)(n0 + i) * 1024 + k0 + tx] = (bf16)tile[tx][i];
}

// ---------------------------------------------------------------------------
// 256x256 pipelined bf16 GEMM: C[M,N] = A[M,K] @ Bt[N,K]^T + bias[N]
// BK=64, 512 threads = 8 waves (2 M-halves x 4 N-quarters), LDS 128KB.
// Per wave: 128x64 output = acc[8][4] floatx4 (128 VGPR).
// LDS layout (bf16 units): A(kb,h,rr,s) = kb*16384 + h*8192 + rr*64 + s*8,
// B at +32768; kb = K-tile parity, h = 128-row half, rr = row-in-half,
// slot s holds logical k-granule s^(rr&7) (m97 granule swizzle —
// conflict-free ds_read_b128, proven in this harness).
// PIPELINE (T3+T4): stage(kt+2) is issued a full iteration before its
// consuming wait; the wait is COUNTED (vmcnt(8) = drain exactly tile kt+1's
// 8 loads, keep kt+2's in flight) — never a same-phase drain (the m97
// structure's ~20% stall). Two barriers per K-tile.
// __launch_bounds__(512, 1): min-BLOCKS semantics (measured r5/r6) -> VGPR
// cap 256; (512,2) would cap at 128 and spill the accumulator (r8 lesson).
// MODE 0: fp32 out row-major; MODE 1: bf16 Q layout [B,H,S,HD] * QSCALE;
// MODE 2: K half -> [B,H,S,HD], V half (col>=1024) -> [B,H,HD,S] transposed.
// ---------------------------------------------------------------------------
__device__ __forceinline__ void stage256(
    const bf16* aptr, const bf16* bptr, int K, bf16* sbase, int kb, int k0) {
  bf16* la = sbase + kb * 16384;
  bf16* lb = sbase + 32768 + kb * 16384;
  #pragma unroll
  for (int h = 0; h < 2; h++)
    #pragma unroll
    for (int p = 0; p < 2; p++) {
      const size_t off = (size_t)(h * 128 + p * 64) * K + k0;
      async_load16(aptr + off, la + h * 8192 + p * 4096);
      async_load16(bptr + off, lb + h * 8192 + p * 4096);
    }
}

template <int MODE>
__device__ __forceinline__ void gemm256_body(
    const bf16* __restrict__ A, const bf16* __restrict__ Bt,
    const float* __restrict__ bias, void* __restrict__ out,
    int N, int K, int bx, int by, bf16* lds) {
  const int tid  = threadIdx.x;
  const int w    = tid >> 6;            // 0..7
  const int lane = tid & 63;
  const int lr   = lane & 15;
  const int lq   = lane >> 4;
  const int wm2  = w >> 2;              // M-half of the wave
  const int wn4  = w & 3;               // N-quarter of the wave
  const int m0   = by * 256;
  const int n0   = bx * 256;
  const int srow = lane >> 3;
  const int sg   = (lane & 7) ^ srow;

  // staging source bases (pre-swizzled granule: slot s holds granule s^(r&7))
  const bf16* aptr = A  + (size_t)(m0 + w * 8 + srow) * K + 8 * sg;
  const bf16* bptr = Bt + (size_t)(n0 + w * 8 + srow) * K + 8 * sg;
  bf16* sbase = lds + w * 512;          // wave's 1KB staging window per half

  // fragment-read bases: a wave reads only its own A-half / B-half
  const int sw0 = 8 * (lq ^ (lr & 7));        // kc=0 granule slot offset
  const int sw1 = 8 * ((4 + lq) ^ (lr & 7));  // kc=1
  const bf16* aB = lds + wm2 * 8192 + lr * 64;
  const bf16* bB = lds + 32768 + (wn4 >> 1) * 8192 + ((wn4 & 1) * 64 + lr) * 64;

  floatx4 acc[8][4];
  #pragma unroll
  for (int i = 0; i < 8; i++)
    #pragma unroll
    for (int j = 0; j < 4; j++) acc[i][j] = floatx4{0.f, 0.f, 0.f, 0.f};

  // prologue: tiles 0 and 1 in flight; wait only for tile 0 (counted)
  stage256(aptr, bptr, K, sbase, 0, 0);
  stage256(aptr, bptr, K, sbase, 1, 64);
  asm volatile("s_waitcnt vmcnt(8)" ::: "memory");
  __syncthreads();

  const int NK = K >> 6;
  for (int kt = 0; kt < NK; kt++) {
    const int kb = kt & 1;
    const bf16* ab = aB + kb * 16384;
    const bf16* bb = bB + kb * 16384;
    bf16x8 af[4], bfv[4];

    // phase 0: row-frags 0-3, kc0 (loads B kc0)
    #pragma unroll
    for (int j = 0; j < 4; j++)
      bfv[j] = *reinterpret_cast<const bf16x8*>(bb + j * 1024 + sw0);
    #pragma unroll
    for (int i = 0; i < 4; i++)
      af[i] = *reinterpret_cast<const bf16x8*>(ab + i * 1024 + sw0);
    __builtin_amdgcn_s_setprio(1);
    #pragma unroll
    for (int i = 0; i < 4; i++)
      #pragma unroll
      for (int j = 0; j < 4; j++)
        acc[i][j] = __builtin_amdgcn_mfma_f32_16x16x32_bf16(af[i], bfv[j], acc[i][j], 0, 0, 0);
    __builtin_amdgcn_s_setprio(0);

    // phase 1: row-frags 4-7, kc0 (B reused)
    #pragma unroll
    for (int i = 0; i < 4; i++)
      af[i] = *reinterpret_cast<const bf16x8*>(ab + (4 + i) * 1024 + sw0);
    __builtin_amdgcn_s_setprio(1);
    #pragma unroll
    for (int i = 0; i < 4; i++)
      #pragma unroll
      for (int j = 0; j < 4; j++)
        acc[4 + i][j] = __builtin_amdgcn_mfma_f32_16x16x32_bf16(af[i], bfv[j], acc[4 + i][j], 0, 0, 0);
    __builtin_amdgcn_s_setprio(0);

    // phase 2: row-frags 0-3, kc1 (loads B kc1)
    #pragma unroll
    for (int j = 0; j < 4; j++)
      bfv[j] = *reinterpret_cast<const bf16x8*>(bb + j * 1024 + sw1);
    #pragma unroll
    for (int i = 0; i < 4; i++)
      af[i] = *reinterpret_cast<const bf16x8*>(ab + i * 1024 + sw1);
    __builtin_amdgcn_s_setprio(1);
    #pragma unroll
    for (int i = 0; i < 4; i++)
      #pragma unroll
      for (int j = 0; j < 4; j++)
        acc[i][j] = __builtin_amdgcn_mfma_f32_16x16x32_bf16(af[i], bfv[j], acc[i][j], 0, 0, 0);
    __builtin_amdgcn_s_setprio(0);

    // phase 3: row-frags 4-7, kc1
    #pragma unroll
    for (int i = 0; i < 4; i++)
      af[i] = *reinterpret_cast<const bf16x8*>(ab + (4 + i) * 1024 + sw1);
    __builtin_amdgcn_s_setprio(1);
    #pragma unroll
    for (int i = 0; i < 4; i++)
      #pragma unroll
      for (int j = 0; j < 4; j++)
        acc[4 + i][j] = __builtin_amdgcn_mfma_f32_16x16x32_bf16(af[i], bfv[j], acc[4 + i][j], 0, 0, 0);
    __builtin_amdgcn_s_setprio(0);

    // B1: all waves finished reading buffer kb -> safe to overwrite
    __syncthreads();
    if (kt + 2 < NK) {
      stage256(aptr, bptr, K, sbase, kb, (kt + 2) * 64);
      asm volatile("s_waitcnt vmcnt(8)" ::: "memory");  // tile kt+1 resident
    } else {
      asm volatile("s_waitcnt vmcnt(0)" ::: "memory");  // tail drain
    }
    __syncthreads();  // B2: tile kt+1 visible to all waves
  }

  // epilogue: acc[i][j] -> row = m0 + wm2*128 + 16i + 4lq + r,
  //                        col = n0 + wn4*64 + 16j + lr
  #pragma unroll
  for (int i = 0; i < 8; i++) {
    int row_base = m0 + wm2 * 128 + 16 * i + lq * 4;
    #pragma unroll
    for (int j = 0; j < 4; j++) {
      int col = n0 + wn4 * 64 + 16 * j + lr;
      float bv = bias[col];
      if (MODE == 2 && col >= 1024) {
        int b = row_base >> 11, s0 = row_base & 2047;
        int c = col - 1024, h = c >> 6, d = c & 63;
        bf16* Vt = (bf16*)out + (size_t)B_ * H_ * S_ * HD_;
        bf16x4 pk;
        #pragma unroll
        for (int r = 0; r < 4; r++) pk[r] = (bf16)(acc[i][j][r] + bv);
        *reinterpret_cast<bf16x4*>(
            &Vt[(((size_t)b * H_ + h) * HD_ + d) * S_ + s0]) = pk;
        continue;
      }
      #pragma unroll
      for (int r = 0; r < 4; r++) {
        int row = row_base + r;
        float v = acc[i][j][r] + bv;
        if (MODE == 0) {
          ((float*)out)[(size_t)row * N + col] = v;
        } else if (MODE == 1) {
          int b = row >> 11, s = row & 2047;
          int h = col >> 6, d = col & 63;
          ((bf16*)out)[(((size_t)b * H_ + h) * S_ + s) * HD_ + d] =
              (bf16)(v * QSCALE);
        } else {
          int b = row >> 11, s = row & 2047;
          int h = col >> 6, d = col & 63;
          ((bf16*)out)[(((size_t)b * H_ + h) * S_ + s) * HD_ + d] = (bf16)v;
        }
      }
    }
  }
}

// Merged Q + KV projections: blocks [0,128) = Q (4x32 tiles of 256^2),
// [128,384) = KV (8x32). 256-col tiles keep each block entirely inside
// the K-half or the V-half of the KV output.
__global__ __launch_bounds__(512, 1) void gemm_qkv(
    const bf16* __restrict__ Xq, const bf16* __restrict__ qwT,
    const float* __restrict__ q_b, bf16* __restrict__ Qb,
    const bf16* __restrict__ Xkv, const bf16* __restrict__ kvwT,
    const float* __restrict__ kv_b, bf16* __restrict__ KVb) {
  __shared__ bf16 lds[65536];  // 128 KB
  int bid = blockIdx.x;
  if (bid < 128)
    gemm256_body<1>(Xq, qwT, q_b, Qb, 1024, 1024, bid & 3, bid >> 2, lds);
  else {
    int b2 = bid - 128;
    gemm256_body<2>(Xkv, kvwT, kv_b, KVb, 2048, 1024, b2 & 7, b2 >> 3, lds);
  }
}

// out-projection (fp32 out): 128 blocks of 256^2
__global__ __launch_bounds__(512, 1) void gemm_out(
    const bf16* __restrict__ A, const bf16* __restrict__ Bt,
    const float* __restrict__ bias, float* __restrict__ out) {
  __shared__ bf16 lds[65536];  // 128 KB
  gemm256_body<0>(A, Bt, bias, out, 1024, 1024, blockIdx.x & 3, blockIdx.x >> 2, lds);
}

// ---------------------------------------------------------------------------
// Attention (r4 kernel, verbatim — best measured: 88.5 µs).
// 256 q-rows/block (4 waves, wave w owns 64 q as 4 groups of 16).
// 3-phase iteration (QK^T A | PV0+QK^T B | PV1), P via per-wave swizzled LDS.
// bh-major grid: the 8 q-tiles of a head share an XCD -> K/V L2-resident
// (measured: FETCH 139MB -> 27.7MB). Pointer-stepped prefetch; setprio(1)
// around the PV MFMA clusters.
// S^T = K@Q^T; p = exp2(s) (scale folded into Q; no running max needed).
// O^T = V^T@P^T with V^T precomputed by the KV GEMM.
// LDS: ks/vts x2 = 32 KB + P 32 KB = 64 KB -> 2 blocks/CU.
// ---------------------------------------------------------------------------
__global__ __launch_bounds__(256, 2) void attn_kernel(
    const bf16* __restrict__ Q, const bf16* __restrict__ Kb,
    const bf16* __restrict__ Vt, bf16* __restrict__ out) {
  __shared__ bf16 smem[32768];  // [2][ks 4096 | vts 4096] | pw 4x4096

  const int tid  = threadIdx.x;
  const int w    = tid >> 6;
  const int lane = tid & 63;
  const int lr   = lane & 15;
  const int lq   = lane >> 4;
  const int bh   = blockIdx.x;          // x-major -> head's q-tiles same XCD
  const int q0   = blockIdx.y * 256;
  const size_t base = (size_t)bh * S_ * HD_;

  bf16* pw = smem + 16384 + w * 4096;  // wave's P: [64 q][64 keys], swizzled

  const int srow = lane >> 3;
  const int sg   = (lane & 7) ^ srow;

  // K/V staging: wave w covers tile rows [16w, 16w+16), 2 DMA instrs each
  const bf16* kptr = Kb + base + (size_t)(16 * w + srow) * HD_ + 8 * sg;
  const bf16* vptr = Vt + base + (size_t)(16 * w + srow) * S_  + 8 * sg;

  // stage tile 0 into buf 0
  #pragma unroll
  for (int p = 0; p < 2; p++) {
    async_load16(kptr + (size_t)8 * p * HD_, smem + (16 * w + 8 * p) * 64);
    async_load16(vptr + (size_t)8 * p * S_,  smem + 4096 + (16 * w + 8 * p) * 64);
  }

  // Q fragments from global (B-layout: n=lr -> q row, k=32kc+8lq+j)
  bf16x8 bq[4][2];
  #pragma unroll
  for (int g = 0; g < 4; g++) {
    const bf16* qrow = Q + base + (size_t)(q0 + 64 * w + 16 * g + lr) * HD_;
    bq[g][0] = *reinterpret_cast<const bf16x8*>(qrow + lq * 8);
    bq[g][1] = *reinterpret_cast<const bf16x8*>(qrow + 32 + lq * 8);
  }

  const int sw0 = 8 * ((0 + lq) ^ (lr & 7));
  const int sw1 = 8 * ((4 + lq) ^ (lr & 7));
  const int pcolbase = 4 * (lq & 1);
  const int pswz = lr & 7;

  float l_i[4] = {0.f, 0.f, 0.f, 0.f};
  floatx4 o_acc[4][4];
  #pragma unroll
  for (int g = 0; g < 4; g++)
    #pragma unroll
    for (int t = 0; t < 4; t++) o_acc[g][t] = floatx4{0.f, 0.f, 0.f, 0.f};

  __syncthreads();  // drain: tile 0 staged (bq loads waited via vmcnt too)

  // pointer-stepped prefetch bases (tile 1), avoids per-iter 64-bit muls
  const bf16* kpf = kptr + (size_t)64 * HD_;
  const bf16* vpf = vptr + 64;

  const int NIT = S_ / 64;
  for (int it = 0; it < NIT; it++) {
    bf16* ks  = smem + (it & 1) * 8192;
    bf16* vts = ks + 4096;

    // prefetch tile it+1 into the other buffer (drained at loop-end barrier)
    if (it + 1 < NIT) {
      bf16* ksn = smem + ((it + 1) & 1) * 8192;
      #pragma unroll
      for (int p = 0; p < 2; p++) {
        async_load16(kpf + (size_t)8 * p * HD_, ksn + (16 * w + 8 * p) * 64);
        async_load16(vpf + (size_t)8 * p * S_,  ksn + 4096 + (16 * w + 8 * p) * 64);
      }
    }

    // QK^T + exp + P-write for one 16-key block t (keys 16t..16t+15)
    auto qkt = [&](int t) {
      bf16x8 ak0 = *reinterpret_cast<const bf16x8*>(ks + (16 * t + lr) * 64 + sw0);
      bf16x8 ak1 = *reinterpret_cast<const bf16x8*>(ks + (16 * t + lr) * 64 + sw1);
      floatx4 sc[4];
      #pragma unroll
      for (int g = 0; g < 4; g++) {
        sc[g] = __builtin_amdgcn_mfma_f32_16x16x32_bf16(ak0, bq[g][0],
                    floatx4{0.f, 0.f, 0.f, 0.f}, 0, 0, 0);
        sc[g] = __builtin_amdgcn_mfma_f32_16x16x32_bf16(ak1, bq[g][1], sc[g], 0, 0, 0);
      }
      const int pcol = 8 * ((2 * t + (lq >> 1)) ^ pswz) + pcolbase;
      #pragma unroll
      for (int g = 0; g < 4; g++) {
        bf16x4 pk;
        float lsum = 0.f;
        #pragma unroll
        for (int r = 0; r < 4; r++) {
          float p = __builtin_amdgcn_exp2f(sc[g][r]);
          lsum += p;
          pk[r] = (bf16)p;
        }
        l_i[g] += lsum;
        *reinterpret_cast<bf16x4*>(&pw[(16 * g + lr) * 64 + pcol]) = pk;
      }
    };

    // ---- phase A: QK^T for keys 0-31 (P chunks 0-3) ----
    qkt(0);
    qkt(1);
    __builtin_amdgcn_wave_barrier();  // pin same-wave ds_write -> ds_read

    // ---- phase B: PV kc=0 (chunks 0-3) overlapped with QK^T t=2,3 ----
    {
      bf16x8 bp0[4], av0[4];
      #pragma unroll
      for (int g = 0; g < 4; g++)
        bp0[g] = *reinterpret_cast<const bf16x8*>(&pw[(16 * g + lr) * 64 + sw0]);
      #pragma unroll
      for (int t2 = 0; t2 < 4; t2++)
        av0[t2] = *reinterpret_cast<const bf16x8*>(vts + (16 * t2 + lr) * 64 + sw0);
      qkt(2);
      __builtin_amdgcn_s_setprio(1);
      #pragma unroll
      for (int t2 = 0; t2 < 2; t2++)
        #pragma unroll
        for (int g = 0; g < 4; g++)
          o_acc[g][t2] = __builtin_amdgcn_mfma_f32_16x16x32_bf16(av0[t2], bp0[g], o_acc[g][t2], 0, 0, 0);
      __builtin_amdgcn_s_setprio(0);
      qkt(3);
      __builtin_amdgcn_s_setprio(1);
      #pragma unroll
      for (int t2 = 2; t2 < 4; t2++)
        #pragma unroll
        for (int g = 0; g < 4; g++)
          o_acc[g][t2] = __builtin_amdgcn_mfma_f32_16x16x32_bf16(av0[t2], bp0[g], o_acc[g][t2], 0, 0, 0);
      __builtin_amdgcn_s_setprio(0);
    }
    __builtin_amdgcn_wave_barrier();  // pin t=2,3 P-writes -> kc=1 reads

    // ---- phase C: PV kc=1 (chunks 4-7) ----
    {
      bf16x8 bp1[4];
      #pragma unroll
      for (int g = 0; g < 4; g++)
        bp1[g] = *reinterpret_cast<const bf16x8*>(&pw[(16 * g + lr) * 64 + sw1]);
      __builtin_amdgcn_s_setprio(1);
      #pragma unroll
      for (int t2 = 0; t2 < 4; t2++) {
        bf16x8 av = *reinterpret_cast<const bf16x8*>(vts + (16 * t2 + lr) * 64 + sw1);
        #pragma unroll
        for (int g = 0; g < 4; g++)
          o_acc[g][t2] = __builtin_amdgcn_mfma_f32_16x16x32_bf16(av, bp1[g], o_acc[g][t2], 0, 0, 0);
      }
      __builtin_amdgcn_s_setprio(0);
    }

    kpf += (size_t)64 * HD_;
    vpf += 64;
    __syncthreads();  // frees cur buf; drains prefetch -> tile it+1 ready
  }

  // finish denom: sum across the 4 lq groups sharing q=lr
  #pragma unroll
  for (int g = 0; g < 4; g++) {
    l_i[g] += __shfl_xor(l_i[g], 16, 64);
    l_i[g] += __shfl_xor(l_i[g], 32, 64);
  }

  // epilogue: out[b, s=q0+64w+16g+lr, h*64 + 16t + 4lq + r]
  const int b = bh >> 4, h = bh & 15;
  #pragma unroll
  for (int g = 0; g < 4; g++) {
    const float inv = 1.0f / l_i[g];
    const int qrow = q0 + 64 * w + 16 * g + lr;
    bf16* orow = out + ((size_t)b * S_ + qrow) * D_ + h * HD_;
    #pragma unroll
    for (int t = 0; t < 4; t++) {
      bf16x4 pk;
      #pragma unroll
      for (int r = 0; r < 4; r++) pk[r] = (bf16)(o_acc[g][t][r] * inv);
      *reinterpret_cast<bf16x4*>(&orow[16 * t + lq * 4]) = pk;
    }
  }
}

// ---------------------------------------------------------------------------
extern "C" void kernel_launch(void* const* d_in, const int* in_sizes, int n_in,
                              void* d_out, int out_size, void* d_ws, size_t ws_size,
                              hipStream_t stream) {
  const float* X_Q   = (const float*)d_in[0];
  const float* X_KV  = (const float*)d_in[1];
  const float* q_w   = (const float*)d_in[2];
  const float* q_b   = (const float*)d_in[3];
  const float* kv_w  = (const float*)d_in[4];
  const float* kv_b  = (const float*)d_in[5];
  const float* out_w = (const float*)d_in[6];
  const float* out_b = (const float*)d_in[7];
  float* out = (float*)d_out;

  char* ws = (char*)d_ws;
  const size_t MB = 1024 * 1024;
  bf16* Xq   = (bf16*)(ws + 0);         // 16MB (reused as attn output later)
  bf16* Xkv  = (bf16*)(ws + 16 * MB);   // 16MB
  bf16* Qb   = (bf16*)(ws + 32 * MB);   // 16MB  [B,H,S,HD] (pre-scaled)
  bf16* Kb   = (bf16*)(ws + 48 * MB);   // 16MB  [B,H,S,HD]; Vt follows at +16MB
  bf16* qwT  = (bf16*)(ws + 80 * MB);   // 2MB   [N=1024][K=1024]
  bf16* kvwT = (bf16*)(ws + 82 * MB);   // 4MB   [N=2048][K=1024]
  bf16* owT  = (bf16*)(ws + 86 * MB);   // 2MB
  bf16* Vt   = Kb + (size_t)B_ * H_ * S_ * HD_;  // [B,H,HD,S]
  bf16* attn = Xq;                       // alias: X_Q bf16 dead after GEMM1

  // merged cast + weight transpose (one launch)
  prep_all<<<20480, 256, 0, stream>>>(X_Q, Xq, X_KV, Xkv,
                                      q_w, qwT, kv_w, kvwT, out_w, owT);
  // merged: Q = (Xq @ q_w + q_b)*QSCALE  and  KV = Xkv @ kv_w + kv_b
  gemm_qkv<<<384, 512, 0, stream>>>(Xq, qwT, q_b, Qb, Xkv, kvwT, kv_b, Kb);
  // attention (r4 kernel: 256 q-rows/block, bh-major grid for XCD/L2)
  attn_kernel<<<dim3(64, 8), 256, 0, stream>>>(Qb, Kb, Vt, attn);
  // out = attn @ out_w + out_b  (fp32)
  gemm_out<<<128, 512, 0, stream>>>(attn, owT, out_b, out);
}